// Round 1
// baseline (71.019 us; speedup 1.0000x reference)
//
#include <hip/hip_runtime.h>
#include <math.h>

// QuantumLayer — analytic collapse of the 16-qubit, 3-layer circuit.
//
// Math (verified against the reference's gate ordering):
//  * RY layer on |0…0> -> product state; per-qubit p(1)=sin^2(θ/2), E[Z_q]=cosθ_q.
//  * Each "phase" diagonal is unit-modulus -> cancels in |ψ|^2.
//  * The CNOT chain CNOT(0,1)…CNOT(14,15) is a GF(2)-linear basis permutation;
//    the measured distribution after 3 layers is the initial product
//    distribution relabeled by L^3 (L = prefix-parity matrix).
//  * (L^3)_{q,k} = C(q-k+2, 2) mod 2 = 1 iff (q-k) mod 4 ∈ {0,1}.
//  => expvals[b,q] = prod_{k<=q, (q-k)%4<2} cos(theta[b,k]);  q_weights unused.
//
// Whole op: theta = x@W_in.T + b_in ; ev as above ; out = ev@W_out.T + b_out.
// ~2 MFLOP, ~290 KB traffic -> launch-overhead bound.

#define BATCH 256
#define DDIM  128
#define NQ    16

__global__ __launch_bounds__(DDIM) void qlayer_kernel(
    const float* __restrict__ x,     // (256,128)
    const float* __restrict__ Win,   // (16,128)
    const float* __restrict__ bin,   // (16)
    const float* __restrict__ Wout,  // (128,16)
    const float* __restrict__ bout,  // (128)
    float* __restrict__ out)         // (256,128)
{
    const int b    = blockIdx.x;
    const int tid  = threadIdx.x;    // 0..127  (2 waves)
    const int wave = tid >> 6;
    const int lane = tid & 63;

    __shared__ float part[2][NQ];
    __shared__ float cosv[NQ];
    __shared__ float ev[NQ];

    const float xv = x[b * DDIM + tid];

    // theta[q] = <x[b,:], W_in[q,:]> : 16 block reductions (shuffle + 2-wave LDS combine)
    #pragma unroll
    for (int q = 0; q < NQ; ++q) {
        float p = xv * Win[q * DDIM + tid];
        #pragma unroll
        for (int off = 32; off > 0; off >>= 1)
            p += __shfl_down(p, off, 64);
        if (lane == 0) part[wave][q] = p;
    }
    __syncthreads();

    if (tid < NQ) {
        const float theta = part[0][tid] + part[1][tid] + bin[tid];
        cosv[tid] = cosf(theta);
    }
    __syncthreads();

    // expvals[q] = prod_{k<=q, (q-k)%4 in {0,1}} cos(theta[k])
    if (tid < NQ) {
        float e = 1.0f;
        for (int k = tid; k >= 0; --k)
            if (((tid - k) & 3) < 2) e *= cosv[k];
        ev[tid] = e;
    }
    __syncthreads();

    // out[b,d] = b_out[d] + sum_q ev[q] * W_out[d,q]
    float acc = bout[tid];
    #pragma unroll
    for (int q = 0; q < NQ; ++q)
        acc += ev[q] * Wout[tid * NQ + q];
    out[b * DDIM + tid] = acc;
}

extern "C" void kernel_launch(void* const* d_in, const int* in_sizes, int n_in,
                              void* d_out, int out_size, void* d_ws, size_t ws_size,
                              hipStream_t stream) {
    const float* x    = (const float*)d_in[0];
    const float* Win  = (const float*)d_in[1];
    const float* bin  = (const float*)d_in[2];
    // d_in[3] = q_weights: provably unused — RZ phases cancel in |psi|^2.
    const float* Wout = (const float*)d_in[4];
    const float* bout = (const float*)d_in[5];
    float* out = (float*)d_out;

    qlayer_kernel<<<BATCH, DDIM, 0, stream>>>(x, Win, bin, Wout, bout, out);
}